// Round 13
// baseline (118.991 us; speedup 1.0000x reference)
//
#include <hip/hip_runtime.h>
#include <math.h>

#define BATCH 2
#define CH 64
#define WID 96
#define HEI 96
#define HWSZ 9216          // 96*96
#define EPSV 1e-8f
#define NCHK 72            // n-chunks of 128 rows (pmax partials per m)
#define MRNG 576           // m per wave-range; 16 ranges
#define NQ 18              // nquad: 4 n-chunks (one per wave) per block

typedef __attribute__((ext_vector_type(8))) short short8v;  // 8 bf16 (4 VGPRs)
typedef __attribute__((ext_vector_type(4))) float f32x4;

__device__ __forceinline__ unsigned short f2bf(float f) {  // RNE bf16
    unsigned u = __float_as_uint(f);
    unsigned r = ((u >> 16) & 1u) + 0x7fffu;
    return (unsigned short)((u + r) >> 16);
}

__device__ __forceinline__ float wave_sum64(float v) {
    #pragma unroll
    for (int m = 1; m < 64; m <<= 1) v += __shfl_xor(v, m, 64);
    return v;
}

// ---- P1: normalize + warp + cosine-sim (R12, unchanged) ----
__global__ __launch_bounds__(256) void normalize_kernel(const float* __restrict__ src,
                                                        const float* __restrict__ tgt,
                                                        const float* __restrict__ flow,
                                                        unsigned short* __restrict__ s_hat,
                                                        unsigned short* __restrict__ t_hat,
                                                        float* __restrict__ csbuf,
                                                        float* __restrict__ out) {
    __shared__ float ss[CH][33];
    __shared__ float tt[CH][33];
    __shared__ float red[2][8][32];
    __shared__ float rinv[2][32];
    __shared__ float nt2[32];
    int b  = blockIdx.x / (HWSZ / 32);
    int p0 = (blockIdx.x % (HWSZ / 32)) * 32;
    int t  = threadIdx.x;

    if (blockIdx.x == 0 && t == 0) out[0] = 0.f;

    #pragma unroll
    for (int r = 0; r < 2; ++r) {
        int c  = r * 32 + (t >> 3);
        int f4 = (t & 7) * 4;
        float4 v = *(const float4*)&src[(size_t)(b * CH + c) * HWSZ + p0 + f4];
        ss[c][f4] = v.x; ss[c][f4 + 1] = v.y; ss[c][f4 + 2] = v.z; ss[c][f4 + 3] = v.w;
        float4 u = *(const float4*)&tgt[(size_t)(b * CH + c) * HWSZ + p0 + f4];
        tt[c][f4] = u.x; tt[c][f4 + 1] = u.y; tt[c][f4 + 2] = u.z; tt[c][f4 + 3] = u.w;
    }
    __syncthreads();

    {
        int q = t >> 5, pl = t & 31;
        float as = 0.f, at = 0.f;
        #pragma unroll
        for (int i = 0; i < 8; ++i) {
            float x = ss[q * 8 + i][pl]; as += x * x;
            float y = tt[q * 8 + i][pl]; at += y * y;
        }
        red[0][q][pl] = as; red[1][q][pl] = at;
    }
    __syncthreads();
    if (t < 64) {
        int which = t >> 5, p = t & 31;
        float n = 0.f;
        #pragma unroll
        for (int g = 0; g < 8; ++g) n += red[which][g][p];
        rinv[which][p] = 1.f / (sqrtf(n) + EPSV);
        if (which == 1) nt2[p] = n;
    }
    __syncthreads();

    #pragma unroll
    for (int r = 0; r < 2; ++r) {
        int e = r * 256 + t;
        int p = e >> 4, c4 = (e & 15) * 4;
        float ri_s = rinv[0][p], ri_t = rinv[1][p];
        ushort4 os, ot;
        os.x = f2bf(ss[c4][p] * ri_s);     os.y = f2bf(ss[c4 + 1][p] * ri_s);
        os.z = f2bf(ss[c4 + 2][p] * ri_s); os.w = f2bf(ss[c4 + 3][p] * ri_s);
        ot.x = f2bf(tt[c4][p] * ri_t);     ot.y = f2bf(tt[c4 + 1][p] * ri_t);
        ot.z = f2bf(tt[c4 + 2][p] * ri_t); ot.w = f2bf(tt[c4 + 3][p] * ri_t);
        *(ushort4*)&s_hat[((size_t)b * HWSZ + p0 + p) * CH + c4] = os;
        *(ushort4*)&t_hat[((size_t)b * HWSZ + p0 + p) * CH + c4] = ot;
    }

    {
        int q = t >> 5, pl = t & 31;
        int m = p0 + pl;
        int y = m / WID, x = m - y * WID;
        int fy = y >> 2, fx = x >> 2;

        float flow_x = flow[((b * 2 + 0) * 24 + fy) * 24 + fx];
        float flow_y = flow[((b * 2 + 1) * 24 + fy) * 24 + fx];

        float gx = 2.f * ((float)x / (WID - 1)) - 1.f + 2.f * flow_x / (float)WID;
        float gy = 2.f * ((float)y / (HEI - 1)) - 1.f + 2.f * flow_y / (float)HEI;
        float sx = (gx + 1.f) * 0.5f * (WID - 1);
        float sy = (gy + 1.f) * 0.5f * (HEI - 1);
        float x0f = floorf(sx), y0f = floorf(sy);
        float wx1 = sx - x0f, wy1 = sy - y0f;
        float wx0 = 1.f - wx1, wy0 = 1.f - wy1;
        int x0 = (int)x0f, y0 = (int)y0f;

        int cx0 = min(max(x0, 0), WID - 1), cx1 = min(max(x0 + 1, 0), WID - 1);
        int cy0 = min(max(y0, 0), HEI - 1), cy1 = min(max(y0 + 1, 0), HEI - 1);
        float ok00 = (x0 >= 0 && x0 < WID && y0 >= 0 && y0 < HEI) ? 1.f : 0.f;
        float ok10 = (x0 + 1 >= 0 && x0 + 1 < WID && y0 >= 0 && y0 < HEI) ? 1.f : 0.f;
        float ok01 = (x0 >= 0 && x0 < WID && y0 + 1 >= 0 && y0 + 1 < HEI) ? 1.f : 0.f;
        float ok11 = (x0 + 1 >= 0 && x0 + 1 < WID && y0 + 1 >= 0 && y0 + 1 < HEI) ? 1.f : 0.f;
        float w00 = wx0 * wy0 * ok00, w10 = wx1 * wy0 * ok10;
        float w01 = wx0 * wy1 * ok01, w11 = wx1 * wy1 * ok11;
        int i00 = cy0 * WID + cx0, i10 = cy0 * WID + cx1;
        int i01 = cy1 * WID + cx0, i11 = cy1 * WID + cx1;

        const float* sb = src + (size_t)b * CH * HWSZ;
        float dot = 0.f, n1 = 0.f;
        #pragma unroll
        for (int i = 0; i < 8; ++i) {
            int c = q * 8 + i;
            const float* sc = sb + (size_t)c * HWSZ;
            float v = w00 * sc[i00] + w10 * sc[i10] + w01 * sc[i01] + w11 * sc[i11];
            float tv = tt[c][pl];
            dot += v * tv; n1 += v * v;
        }
        __syncthreads();
        red[0][q][pl] = dot; red[1][q][pl] = n1;
        __syncthreads();
        if (t < 32) {
            float d = 0.f, a1 = 0.f;
            #pragma unroll
            for (int g = 0; g < 8; ++g) { d += red[0][g][pl]; a1 += red[1][g][pl]; }
            float cs = d / (fmaxf(sqrtf(a1), EPSV) * fmaxf(sqrtf(nt2[pl]), EPSV));
            csbuf[(size_t)b * HWSZ + p0 + pl] = cs;
        }
    }
}

// ---- P2: corrmax — barrier-free, LDS-free, A-in-registers ----
// Wave = (b, n-chunk of 128 rows in 16 reg A-frags, 576-m range).
// Block's 4 waves share the m-range (B-stream L1-shared) with 4 n-chunks.
// grid = (NQ, 16 m-ranges, BATCH); no __syncthreads anywhere.
__global__ __launch_bounds__(256) void corrmax_kernel(const unsigned short* __restrict__ s_hat,
                                                      const unsigned short* __restrict__ t_hat,
                                                      float* __restrict__ pmax) {
    int t = threadIdx.x;
    int w = t >> 6, lane = t & 63;
    int lrow = lane & 15;                 // row-in-group
    int g16  = lane >> 4;                 // k-slot (8 bf16)
    int b   = blockIdx.z;
    int m0  = blockIdx.y * MRNG;
    int nch = blockIdx.x * 4 + w;         // 0..71
    int n0  = nch * 128;
    const size_t bofs = (size_t)b * HWSZ * CH;

    // A-frags: 8 n-groups x 2 k-halves = 64 VGPR, loaded once (coalesced)
    short8v af[8][2];
    #pragma unroll
    for (int ng = 0; ng < 8; ++ng) {
        const unsigned short* p = s_hat + bofs + (size_t)(n0 + ng * 16 + lrow) * CH + g16 * 8;
        af[ng][0] = *(const short8v*)p;
        af[ng][1] = *(const short8v*)(p + 32);
    }

    f32x4 zero = {0.f, 0.f, 0.f, 0.f};
    float* pout = pmax + ((size_t)b * NCHK + nch) * HWSZ + m0;

    // m-loop: 36 groups of 16, B prefetched one iteration ahead
    const unsigned short* bp = t_hat + bofs + (size_t)(m0 + lrow) * CH + g16 * 8;
    short8v b0 = *(const short8v*)bp;
    short8v b1 = *(const short8v*)(bp + 32);
    bp += 16 * CH;

    #pragma unroll 1
    for (int mg = 0; mg < MRNG / 16; ++mg) {
        short8v nb0, nb1;
        if (mg < MRNG / 16 - 1) {
            nb0 = *(const short8v*)bp;
            nb1 = *(const short8v*)(bp + 32);
            bp += 16 * CH;
        }
        f32x4 acc[8];
        #pragma unroll
        for (int ng = 0; ng < 8; ++ng) {
            acc[ng] = __builtin_amdgcn_mfma_f32_16x16x32_bf16(af[ng][0], b0, zero, 0, 0, 0);
            acc[ng] = __builtin_amdgcn_mfma_f32_16x16x32_bf16(af[ng][1], b1, acc[ng], 0, 0, 0);
        }
        // max over the 128 n-rows: per-lane fold (32 vals) + shfl over row quarters
        float mx = -INFINITY;
        #pragma unroll
        for (int ng = 0; ng < 8; ++ng) {
            float t3 = fmaxf(fmaxf(acc[ng][0], acc[ng][1]), acc[ng][2]);   // v_max3
            mx = fmaxf(fmaxf(t3, acc[ng][3]), mx);                          // v_max3
        }
        mx = fmaxf(mx, __shfl_xor(mx, 16, 64));
        mx = fmaxf(mx, __shfl_xor(mx, 32, 64));
        if (g16 == 0) pout[mg * 16 + lrow] = mx;
        b0 = nb0; b1 = nb1;
    }
}

// ---- P3: finalize — 72-partial cmax reduce + loss map + mean ----
__global__ __launch_bounds__(256) void finalize_kernel(const float* __restrict__ csbuf,
                                                       const float* __restrict__ pmax,
                                                       const float* __restrict__ att,
                                                       float* __restrict__ out) {
    __shared__ float sdata[4];
    int tid = blockIdx.x * 256 + threadIdx.x;
    int b = tid / HWSZ, m = tid - b * HWSZ;
    int y = m / WID, x = m - y * WID;
    int fy = y >> 2, fx = x >> 2;

    const float* pp = pmax + (size_t)b * NCHK * HWSZ + m;
    float cm = -INFINITY;
    #pragma unroll 8
    for (int ch = 0; ch < NCHK; ++ch)
        cm = fmaxf(cm, pp[(size_t)ch * HWSZ]);
    float cs = csbuf[tid];
    float a  = att[(b * 24 + fy) * 24 + fx];
    float contrib = a * (expf(-cs / (cm + EPSV)) - 0.36787944117144233f);

    contrib = wave_sum64(contrib);
    int t = threadIdx.x;
    if ((t & 63) == 0) sdata[t >> 6] = contrib;
    __syncthreads();
    if (t == 0)
        atomicAdd(out, (sdata[0] + sdata[1] + sdata[2] + sdata[3])
                         * (1.0f / (float)(BATCH * HWSZ)));
}

extern "C" void kernel_launch(void* const* d_in, const int* in_sizes, int n_in,
                              void* d_out, int out_size, void* d_ws, size_t ws_size,
                              hipStream_t stream) {
    const float* target_vgg = (const float*)d_in[0];
    const float* source_vgg = (const float*)d_in[1];
    const float* flow       = (const float*)d_in[2];
    const float* attention  = (const float*)d_in[3];
    float* out = (float*)d_out;

    unsigned short* s_hat = (unsigned short*)d_ws;                       // B*HW*C bf16
    unsigned short* t_hat = s_hat + (size_t)BATCH * HWSZ * CH;           // B*HW*C bf16
    float* pmax  = (float*)(t_hat + (size_t)BATCH * HWSZ * CH);          // B*NCHK*HW f32
    float* csbuf = pmax + (size_t)BATCH * NCHK * HWSZ;                   // B*HW f32

    normalize_kernel<<<BATCH * HWSZ / 32, 256, 0, stream>>>(source_vgg, target_vgg, flow,
                                                            s_hat, t_hat, csbuf, out);
    dim3 g2(NQ, HWSZ / MRNG, BATCH);
    corrmax_kernel<<<g2, 256, 0, stream>>>(s_hat, t_hat, pmax);
    finalize_kernel<<<BATCH * HWSZ / 256, 256, 0, stream>>>(csbuf, pmax, attention, out);
}

// Round 14
// 96.726 us; speedup vs baseline: 1.2302x; 1.2302x over previous
//
#include <hip/hip_runtime.h>
#include <math.h>

#define BATCH 2
#define CH 64
#define WID 96
#define HEI 96
#define HWSZ 9216          // 96*96
#define EPSV 1e-8f
#define NSEG 8             // n segments
#define SEGROWS 1152       // HWSZ/NSEG
#define CHROWS 128         // rows per staged LDS chunk (16 KB)
#define NCH 9              // SEGROWS/CHROWS
#define MTILE 256          // m per block = 4 waves x 64

typedef __attribute__((ext_vector_type(8))) short short8v;  // 8 bf16 (4 VGPRs)
typedef __attribute__((ext_vector_type(4))) float f32x4;

// order-preserving float<->uint encoding for atomicMax on floats
__device__ __forceinline__ unsigned enc_f(float f) {
    unsigned u = __float_as_uint(f);
    return (u & 0x80000000u) ? ~u : (u | 0x80000000u);
}
__device__ __forceinline__ float dec_f(unsigned u) {
    unsigned b = (u & 0x80000000u) ? (u ^ 0x80000000u) : ~u;
    return __uint_as_float(b);
}

__device__ __forceinline__ unsigned short f2bf(float f) {  // RNE bf16
    unsigned u = __float_as_uint(f);
    unsigned r = ((u >> 16) & 1u) + 0x7fffu;
    return (unsigned short)((u + r) >> 16);
}

__device__ __forceinline__ float wave_sum64(float v) {
    #pragma unroll
    for (int m = 1; m < 64; m <<= 1) v += __shfl_xor(v, m, 64);
    return v;
}

// async global->LDS, 16B per lane; LDS dest = wave-uniform base + lane*16
__device__ __forceinline__ void gload_lds16(const void* g, void* l) {
    __builtin_amdgcn_global_load_lds(
        (const __attribute__((address_space(1))) unsigned int*)g,
        (__attribute__((address_space(3))) unsigned int*)l, 16, 0, 0);
}

// ---- P1: normalize + warp + cosine-sim; also inits cmax to enc(-inf) ----
__global__ __launch_bounds__(256) void normalize_kernel(const float* __restrict__ src,
                                                        const float* __restrict__ tgt,
                                                        const float* __restrict__ flow,
                                                        unsigned short* __restrict__ s_hat,
                                                        unsigned short* __restrict__ t_hat,
                                                        float* __restrict__ csbuf,
                                                        unsigned* __restrict__ cmax,
                                                        float* __restrict__ out) {
    __shared__ float ss[CH][33];
    __shared__ float tt[CH][33];
    __shared__ float red[2][8][32];
    __shared__ float rinv[2][32];
    __shared__ float nt2[32];
    int b  = blockIdx.x / (HWSZ / 32);
    int p0 = (blockIdx.x % (HWSZ / 32)) * 32;
    int t  = threadIdx.x;

    if (blockIdx.x == 0 && t == 0) out[0] = 0.f;
    if (t < 32) cmax[(size_t)b * HWSZ + p0 + t] = 0x007FFFFFu;   // enc(-inf)

    // stage both inputs' 32-position tiles (coalesced float4)
    #pragma unroll
    for (int r = 0; r < 2; ++r) {
        int c  = r * 32 + (t >> 3);
        int f4 = (t & 7) * 4;
        float4 v = *(const float4*)&src[(size_t)(b * CH + c) * HWSZ + p0 + f4];
        ss[c][f4] = v.x; ss[c][f4 + 1] = v.y; ss[c][f4 + 2] = v.z; ss[c][f4 + 3] = v.w;
        float4 u = *(const float4*)&tgt[(size_t)(b * CH + c) * HWSZ + p0 + f4];
        tt[c][f4] = u.x; tt[c][f4 + 1] = u.y; tt[c][f4 + 2] = u.z; tt[c][f4 + 3] = u.w;
    }
    __syncthreads();

    // per-position sumsq over channels
    {
        int q = t >> 5, pl = t & 31;
        float as = 0.f, at = 0.f;
        #pragma unroll
        for (int i = 0; i < 8; ++i) {
            float x = ss[q * 8 + i][pl]; as += x * x;
            float y = tt[q * 8 + i][pl]; at += y * y;
        }
        red[0][q][pl] = as; red[1][q][pl] = at;
    }
    __syncthreads();
    if (t < 64) {
        int which = t >> 5, p = t & 31;
        float n = 0.f;
        #pragma unroll
        for (int g = 0; g < 8; ++g) n += red[which][g][p];
        rinv[which][p] = 1.f / (sqrtf(n) + EPSV);
        if (which == 1) nt2[p] = n;     // target ||.||^2, reused for cos-sim
    }
    __syncthreads();

    // write normalized bf16 vectors (coalesced ushort4)
    #pragma unroll
    for (int r = 0; r < 2; ++r) {
        int e = r * 256 + t;
        int p = e >> 4, c4 = (e & 15) * 4;
        float ri_s = rinv[0][p], ri_t = rinv[1][p];
        ushort4 os, ot;
        os.x = f2bf(ss[c4][p] * ri_s);     os.y = f2bf(ss[c4 + 1][p] * ri_s);
        os.z = f2bf(ss[c4 + 2][p] * ri_s); os.w = f2bf(ss[c4 + 3][p] * ri_s);
        ot.x = f2bf(tt[c4][p] * ri_t);     ot.y = f2bf(tt[c4 + 1][p] * ri_t);
        ot.z = f2bf(tt[c4 + 2][p] * ri_t); ot.w = f2bf(tt[c4 + 3][p] * ri_t);
        *(ushort4*)&s_hat[((size_t)b * HWSZ + p0 + p) * CH + c4] = os;
        *(ushort4*)&t_hat[((size_t)b * HWSZ + p0 + p) * CH + c4] = ot;
    }

    // ---- bilinear warp + cosine sim (independent of corrmax) ----
    {
        int q = t >> 5, pl = t & 31;
        int m = p0 + pl;
        int y = m / WID, x = m - y * WID;
        int fy = y >> 2, fx = x >> 2;   // nearest: (i*24)//96 == i//4

        float flow_x = flow[((b * 2 + 0) * 24 + fy) * 24 + fx];
        float flow_y = flow[((b * 2 + 1) * 24 + fy) * 24 + fx];

        float gx = 2.f * ((float)x / (WID - 1)) - 1.f + 2.f * flow_x / (float)WID;
        float gy = 2.f * ((float)y / (HEI - 1)) - 1.f + 2.f * flow_y / (float)HEI;
        float sx = (gx + 1.f) * 0.5f * (WID - 1);
        float sy = (gy + 1.f) * 0.5f * (HEI - 1);
        float x0f = floorf(sx), y0f = floorf(sy);
        float wx1 = sx - x0f, wy1 = sy - y0f;
        float wx0 = 1.f - wx1, wy0 = 1.f - wy1;
        int x0 = (int)x0f, y0 = (int)y0f;

        int cx0 = min(max(x0, 0), WID - 1), cx1 = min(max(x0 + 1, 0), WID - 1);
        int cy0 = min(max(y0, 0), HEI - 1), cy1 = min(max(y0 + 1, 0), HEI - 1);
        float ok00 = (x0 >= 0 && x0 < WID && y0 >= 0 && y0 < HEI) ? 1.f : 0.f;
        float ok10 = (x0 + 1 >= 0 && x0 + 1 < WID && y0 >= 0 && y0 < HEI) ? 1.f : 0.f;
        float ok01 = (x0 >= 0 && x0 < WID && y0 + 1 >= 0 && y0 + 1 < HEI) ? 1.f : 0.f;
        float ok11 = (x0 + 1 >= 0 && x0 + 1 < WID && y0 + 1 >= 0 && y0 + 1 < HEI) ? 1.f : 0.f;
        float w00 = wx0 * wy0 * ok00, w10 = wx1 * wy0 * ok10;
        float w01 = wx0 * wy1 * ok01, w11 = wx1 * wy1 * ok11;
        int i00 = cy0 * WID + cx0, i10 = cy0 * WID + cx1;
        int i01 = cy1 * WID + cx0, i11 = cy1 * WID + cx1;

        const float* sb = src + (size_t)b * CH * HWSZ;
        float dot = 0.f, n1 = 0.f;
        #pragma unroll
        for (int i = 0; i < 8; ++i) {
            int c = q * 8 + i;
            const float* sc = sb + (size_t)c * HWSZ;
            float v = w00 * sc[i00] + w10 * sc[i10] + w01 * sc[i01] + w11 * sc[i11];
            float tv = tt[c][pl];          // target from LDS (no global re-read)
            dot += v * tv; n1 += v * v;
        }
        __syncthreads();                    // red[] reuse (phase B done)
        red[0][q][pl] = dot; red[1][q][pl] = n1;
        __syncthreads();
        if (t < 32) {
            float d = 0.f, a1 = 0.f;
            #pragma unroll
            for (int g = 0; g < 8; ++g) { d += red[0][g][pl]; a1 += red[1][g][pl]; }
            float cs = d / (fmaxf(sqrtf(a1), EPSV) * fmaxf(sqrtf(nt2[pl]), EPSV));
            csbuf[(size_t)b * HWSZ + p0 + pl] = cs;
        }
    }
}

// ---- P2: corrmax — MFMA GEMM-with-max, 2-phase LDS dbuf (R12 structure) ----
// Final per-wave maxes go through atomicMax(enc) into cmax[b][m] (8 writers
// per address). grid = (36 mtiles, NSEG, BATCH); 4 waves x 64 m per block.
__global__ __launch_bounds__(256) void corrmax_kernel(const unsigned short* __restrict__ s_hat,
                                                      const unsigned short* __restrict__ t_hat,
                                                      unsigned* __restrict__ cmax) {
    __shared__ short8v abuf_v[2048];            // 32 KB = 2 x 16 KB double buffer
    char* abuf = (char*)abuf_v;
    int t = threadIdx.x;
    int w = t >> 6, lane = t & 63;
    int lrow = lane & 15;                       // row-in-group
    int g16  = lane >> 4;                       // k-slot (8 bf16)
    int b      = blockIdx.z;
    int nseg   = blockIdx.y;
    int n0     = nseg * SEGROWS;
    int m_base = blockIdx.x * MTILE + w * 64;
    const size_t bofs = (size_t)b * HWSZ * CH;

    short8v bf[4][2];
    #pragma unroll
    for (int gm = 0; gm < 4; ++gm) {
        const unsigned short* p = t_hat + bofs + (size_t)(m_base + gm * 16 + lrow) * CH + g16 * 8;
        bf[gm][0] = *(const short8v*)p;
        bf[gm][1] = *(const short8v*)(p + 32);
    }

    const char* gseg = (const char*)(s_hat + bofs + (size_t)n0 * CH);

    // stage chunk 0 (linear LDS dest, pre-swizzled global src, rule #21)
    #pragma unroll
    for (int k = 0; k < 4; ++k) {
        int o = w * 4096 + k * 1024 + lane * 16;
        int so = o ^ (((o >> 7) & 7) << 4);
        gload_lds16(gseg + so, abuf + w * 4096 + k * 1024);
    }

    f32x4 zero = {0.f, 0.f, 0.f, 0.f};
    float rmax[4] = {-INFINITY, -INFINITY, -INFINITY, -INFINITY};

    int lb0 = lrow * 128 + ((g16       ^ (lrow & 7)) << 4);
    int lb1 = lrow * 128 + (((g16 + 4) ^ (lrow & 7)) << 4);

    __syncthreads();   // vmcnt drain -> chunk 0 visible

    for (int c = 0; c < NCH; ++c) {
        const char* cur = abuf + (c & 1) * 16384;
        if (c + 1 < NCH) {                      // STAGE next chunk first
            const char* gch = gseg + (size_t)(c + 1) * CHROWS * 128;
            char* nxt = abuf + ((c + 1) & 1) * 16384;
            #pragma unroll
            for (int k = 0; k < 4; ++k) {
                int o = w * 4096 + k * 1024 + lane * 16;
                int so = o ^ (((o >> 7) & 7) << 4);
                gload_lds16(gch + so, nxt + w * 4096 + k * 1024);
            }
        }
        #pragma unroll 2
        for (int ng = 0; ng < 8; ++ng) {        // COMPUTE current chunk
            short8v a0 = *(const short8v*)(cur + ng * 2048 + lb0);
            short8v a1 = *(const short8v*)(cur + ng * 2048 + lb1);
            #pragma unroll
            for (int gm = 0; gm < 4; ++gm) {
                f32x4 acc = __builtin_amdgcn_mfma_f32_16x16x32_bf16(a0, bf[gm][0], zero, 0, 0, 0);
                acc = __builtin_amdgcn_mfma_f32_16x16x32_bf16(a1, bf[gm][1], acc, 0, 0, 0);
                float t3 = fmaxf(fmaxf(acc[0], acc[1]), acc[2]);     // v_max3
                rmax[gm] = fmaxf(fmaxf(t3, acc[3]), rmax[gm]);       // v_max3
            }
        }
        __syncthreads();   // vmcnt drain (next staged) + WAR protection
    }

    #pragma unroll
    for (int gm = 0; gm < 4; ++gm) {
        float v = rmax[gm];
        v = fmaxf(v, __shfl_xor(v, 16, 64));
        v = fmaxf(v, __shfl_xor(v, 32, 64));
        if (g16 == 0)
            atomicMax(&cmax[(size_t)b * HWSZ + m_base + gm * 16 + lrow], enc_f(v));
    }
}

// ---- P3: finalize — decode cmax + loss map + mean (tiny) ----
__global__ __launch_bounds__(256) void finalize_kernel(const float* __restrict__ csbuf,
                                                       const unsigned* __restrict__ cmax,
                                                       const float* __restrict__ att,
                                                       float* __restrict__ out) {
    __shared__ float sdata[4];
    int tid = blockIdx.x * 256 + threadIdx.x;
    int b = tid / HWSZ, m = tid - b * HWSZ;
    int y = m / WID, x = m - y * WID;
    int fy = y >> 2, fx = x >> 2;

    float cm = dec_f(cmax[tid]);
    float cs = csbuf[tid];
    float a  = att[(b * 24 + fy) * 24 + fx];
    float contrib = a * (expf(-cs / (cm + EPSV)) - 0.36787944117144233f);

    contrib = wave_sum64(contrib);
    int t = threadIdx.x;
    if ((t & 63) == 0) sdata[t >> 6] = contrib;
    __syncthreads();
    if (t == 0)
        atomicAdd(out, (sdata[0] + sdata[1] + sdata[2] + sdata[3])
                         * (1.0f / (float)(BATCH * HWSZ)));
}

extern "C" void kernel_launch(void* const* d_in, const int* in_sizes, int n_in,
                              void* d_out, int out_size, void* d_ws, size_t ws_size,
                              hipStream_t stream) {
    const float* target_vgg = (const float*)d_in[0];
    const float* source_vgg = (const float*)d_in[1];
    const float* flow       = (const float*)d_in[2];
    const float* attention  = (const float*)d_in[3];
    float* out = (float*)d_out;

    unsigned short* s_hat = (unsigned short*)d_ws;                       // B*HW*C bf16
    unsigned short* t_hat = s_hat + (size_t)BATCH * HWSZ * CH;           // B*HW*C bf16
    unsigned* cmax = (unsigned*)(t_hat + (size_t)BATCH * HWSZ * CH);     // B*HW u32
    float* csbuf   = (float*)(cmax + (size_t)BATCH * HWSZ);              // B*HW f32

    normalize_kernel<<<BATCH * HWSZ / 32, 256, 0, stream>>>(source_vgg, target_vgg, flow,
                                                            s_hat, t_hat, csbuf, cmax, out);
    dim3 g2(HWSZ / MTILE, NSEG, BATCH);
    corrmax_kernel<<<g2, 256, 0, stream>>>(s_hat, t_hat, cmax);
    finalize_kernel<<<BATCH * HWSZ / 256, 256, 0, stream>>>(csbuf, cmax, attention, out);
}